// Round 3
// baseline (236.462 us; speedup 1.0000x reference)
//
#include <hip/hip_runtime.h>
#include <hip/hip_bf16.h>

#define B_  2
#define S_  2048
#define H_  1024
#define NH_ 16
#define HD_ 64
#define EPSLN 1e-12f

typedef short bf16x8 __attribute__((ext_vector_type(8)));
typedef float f32x4  __attribute__((ext_vector_type(4)));

__device__ __forceinline__ float bf2f(ushort u) {
    union { unsigned int i; float f; } v; v.i = ((unsigned int)u) << 16; return v.f;
}
__device__ __forceinline__ ushort f2bf(float f) {
    union { float f; unsigned int i; } v; v.f = f;
    unsigned int r = v.i + 0x7FFFu + ((v.i >> 16) & 1u);   // RNE
    return (ushort)(r >> 16);
}

// ---------------------------------------------------------------- fp32 -> bf16 convert
__global__ __launch_bounds__(256) void cvt_f32_bf16(const float* __restrict__ in,
                                                    ushort* __restrict__ out, int n) {
    int i = (blockIdx.x * 256 + threadIdx.x) * 4;
    float4 v = *(const float4*)&in[i];
    ushort4 o = make_ushort4(f2bf(v.x), f2bf(v.y), f2bf(v.z), f2bf(v.w));
    *(ushort4*)&out[i] = o;
}

// ---------------------------------------------------------------- transpose + convert
// 1024x1024 fp32 -> transposed bf16, 64x64 tiles
__global__ __launch_bounds__(256) void transpose_cvt(
        const float* __restrict__ W0, const float* __restrict__ W1,
        const float* __restrict__ W2, const float* __restrict__ W3,
        ushort* __restrict__ T0, ushort* __restrict__ T1,
        ushort* __restrict__ T2, ushort* __restrict__ T3) {
    const int z = blockIdx.z;
    const float* in = (z == 0) ? W0 : (z == 1) ? W1 : (z == 2) ? W2 : W3;
    ushort* out     = (z == 0) ? T0 : (z == 1) ? T1 : (z == 2) ? T2 : T3;

    __shared__ float tile[64][65];
    const int bx = blockIdx.x * 64, by = blockIdx.y * 64;
    const int t = threadIdx.x;
    #pragma unroll
    for (int i = 0; i < 16; i++) {
        int idx = t + i * 256;           // 0..4095
        int r = idx >> 6, c = idx & 63;
        tile[r][c] = in[(by + r) * 1024 + bx + c];
    }
    __syncthreads();
    #pragma unroll
    for (int i = 0; i < 16; i++) {
        int idx = t + i * 256;
        int r = idx >> 6, c = idx & 63;
        out[(bx + r) * 1024 + by + c] = f2bf(tile[c][r]);
    }
}

// ---------------------------------------------------------------- QKV GEMM
// X[4096][1024](bf16) @ W (via W^T bf16) + bias(f32) -> [B,NH,S,HD] bf16
__global__ __launch_bounds__(256) void qkv_gemm(
        const ushort* __restrict__ X,
        const ushort* __restrict__ Wqt, const ushort* __restrict__ Wkt, const ushort* __restrict__ Wvt,
        const float* __restrict__ bq,  const float* __restrict__ bk,  const float* __restrict__ bv,
        ushort* __restrict__ Qo, ushort* __restrict__ Ko, ushort* __restrict__ Vo) {
    const int which = blockIdx.z;
    const ushort* Wt  = (which == 0) ? Wqt : (which == 1) ? Wkt : Wvt;
    const float* bias = (which == 0) ? bq  : (which == 1) ? bk  : bv;
    ushort* Out       = (which == 0) ? Qo  : (which == 1) ? Ko  : Vo;

    __shared__ ushort As[128][72];
    __shared__ ushort Bs[128][72];
    const int m0 = blockIdx.x * 128, n0 = blockIdx.y * 128;
    const int t = threadIdx.x;
    const int lane = t & 63, w = t >> 6;
    const int wr = (w >> 1) * 64, wc = (w & 1) * 64;
    const int l15 = lane & 15, l4 = lane >> 4;

    f32x4 acc[4][4] = {};
    const int sr = t >> 3, sc = (t & 7) * 8;

    for (int k0 = 0; k0 < H_; k0 += 64) {
        __syncthreads();
        #pragma unroll
        for (int p = 0; p < 4; p++) {
            uint4 av  = *(const uint4*)&X [(m0 + p * 32 + sr) * H_ + k0 + sc];
            uint4 bv2 = *(const uint4*)&Wt[(n0 + p * 32 + sr) * H_ + k0 + sc];
            *(uint4*)&As[p * 32 + sr][sc] = av;
            *(uint4*)&Bs[p * 32 + sr][sc] = bv2;
        }
        __syncthreads();
        #pragma unroll
        for (int ks = 0; ks < 2; ks++) {
            bf16x8 af[4], bfr[4];
            #pragma unroll
            for (int i = 0; i < 4; i++) af[i]  = *(const bf16x8*)&As[wr + i * 16 + l15][ks * 32 + l4 * 8];
            #pragma unroll
            for (int i = 0; i < 4; i++) bfr[i] = *(const bf16x8*)&Bs[wc + i * 16 + l15][ks * 32 + l4 * 8];
            #pragma unroll
            for (int mi = 0; mi < 4; mi++)
                #pragma unroll
                for (int ni = 0; ni < 4; ni++)
                    acc[mi][ni] = __builtin_amdgcn_mfma_f32_16x16x32_bf16(af[mi], bfr[ni], acc[mi][ni], 0, 0, 0);
        }
    }

    #pragma unroll
    for (int ni = 0; ni < 4; ni++) {
        int n = n0 + wc + ni * 16 + l15;
        float bvf = bias[n];
        int h = n >> 6, d = n & 63;
        #pragma unroll
        for (int mi = 0; mi < 4; mi++) {
            int mrow = m0 + wr + mi * 16 + l4 * 4;
            #pragma unroll
            for (int j = 0; j < 4; j++) {
                int m = mrow + j;
                int b = m >> 11, s = m & 2047;
                Out[((b * NH_ + h) * S_ + s) * HD_ + d] = f2bf(acc[mi][ni][j] + bvf);
            }
        }
    }
}

// ---------------------------------------------------------------- flash attention
// Q,K,V: [B,NH,S,HD] bf16, mask f32 [B,S] -> ctx: [B,S,H] bf16
__global__ __launch_bounds__(256) void flash_attn(
        const ushort* __restrict__ Q, const ushort* __restrict__ K, const ushort* __restrict__ V,
        const float* __restrict__ mask, ushort* __restrict__ ctx) {
    __shared__ ushort Ks[64][72];
    __shared__ ushort Vs[64][72];
    __shared__ ushort Ps[4][16][72];

    const int qt = blockIdx.x, h = blockIdx.y, b = blockIdx.z;
    const int t = threadIdx.x, lane = t & 63, w = t >> 6;
    const int l15 = lane & 15, l4 = lane >> 4;
    const size_t head_off = ((size_t)(b * NH_ + h)) * S_ * HD_;
    const ushort* Qh = Q + head_off;
    const ushort* Kh = K + head_off;
    const ushort* Vh = V + head_off;

    const int qrow = qt * 64 + w * 16 + l15;
    bf16x8 qf[2];
    qf[0] = *(const bf16x8*)&Qh[qrow * 64 + 0  + l4 * 8];
    qf[1] = *(const bf16x8*)&Qh[qrow * 64 + 32 + l4 * 8];

    f32x4 ctx_acc[4] = {};
    float mrun[4], lrun[4];
    #pragma unroll
    for (int j = 0; j < 4; j++) { mrun[j] = -1e30f; lrun[j] = 0.f; }

    const int sr = t >> 2, sc0 = (t & 3) * 8;

    for (int kv0 = 0; kv0 < S_; kv0 += 64) {
        __syncthreads();
        {
            uint4 k1 = *(const uint4*)&Kh[(kv0 + sr) * 64 + sc0];
            uint4 k2 = *(const uint4*)&Kh[(kv0 + sr) * 64 + sc0 + 32];
            uint4 v1 = *(const uint4*)&Vh[(kv0 + sr) * 64 + sc0];
            uint4 v2 = *(const uint4*)&Vh[(kv0 + sr) * 64 + sc0 + 32];
            *(uint4*)&Ks[sr][sc0]      = k1;
            *(uint4*)&Ks[sr][sc0 + 32] = k2;
            *(uint4*)&Vs[sr][sc0]      = v1;
            *(uint4*)&Vs[sr][sc0 + 32] = v2;
        }
        __syncthreads();

        // QK^T: sacc[n] : rows q_local = l4*4+j, cols kv_local = n*16+l15
        f32x4 sacc[4] = {};
        #pragma unroll
        for (int ks = 0; ks < 2; ks++) {
            bf16x8 kf[4];
            #pragma unroll
            for (int n = 0; n < 4; n++) kf[n] = *(const bf16x8*)&Ks[n * 16 + l15][ks * 32 + l4 * 8];
            #pragma unroll
            for (int n = 0; n < 4; n++)
                sacc[n] = __builtin_amdgcn_mfma_f32_16x16x32_bf16(qf[ks], kf[n], sacc[n], 0, 0, 0);
        }

        float sv[4][4], tmax[4];
        #pragma unroll
        for (int j = 0; j < 4; j++) tmax[j] = -1e30f;
        #pragma unroll
        for (int n = 0; n < 4; n++) {
            float mk = mask[b * S_ + kv0 + n * 16 + l15];
            #pragma unroll
            for (int j = 0; j < 4; j++) {
                float x = sacc[n][j] * 0.125f + mk;
                sv[n][j] = x;
                tmax[j] = fmaxf(tmax[j], x);
            }
        }
        #pragma unroll
        for (int m = 1; m < 16; m <<= 1)
            #pragma unroll
            for (int j = 0; j < 4; j++) tmax[j] = fmaxf(tmax[j], __shfl_xor(tmax[j], m, 64));

        float scale_j[4], tsum[4];
        #pragma unroll
        for (int j = 0; j < 4; j++) {
            float mnew = fmaxf(mrun[j], tmax[j]);
            scale_j[j] = __expf(mrun[j] - mnew);
            mrun[j] = mnew;
            tsum[j] = 0.f;
        }
        #pragma unroll
        for (int n = 0; n < 4; n++)
            #pragma unroll
            for (int j = 0; j < 4; j++) {
                float p = __expf(sv[n][j] - mrun[j]);
                tsum[j] += p;
                Ps[w][l4 * 4 + j][n * 16 + l15] = f2bf(p);
            }
        #pragma unroll
        for (int m = 1; m < 16; m <<= 1)
            #pragma unroll
            for (int j = 0; j < 4; j++) tsum[j] += __shfl_xor(tsum[j], m, 64);
        #pragma unroll
        for (int j = 0; j < 4; j++) lrun[j] = lrun[j] * scale_j[j] + tsum[j];

        #pragma unroll
        for (int df = 0; df < 4; df++)
            #pragma unroll
            for (int j = 0; j < 4; j++) ctx_acc[df][j] *= scale_j[j];

        // PV
        #pragma unroll
        for (int ks = 0; ks < 2; ks++) {
            bf16x8 pf = *(const bf16x8*)&Ps[w][l15][ks * 32 + l4 * 8];
            #pragma unroll
            for (int df = 0; df < 4; df++) {
                bf16x8 vf;
                #pragma unroll
                for (int i = 0; i < 8; i++)
                    ((short*)&vf)[i] = (short)Vs[ks * 32 + l4 * 8 + i][df * 16 + l15];
                ctx_acc[df] = __builtin_amdgcn_mfma_f32_16x16x32_bf16(pf, vf, ctx_acc[df], 0, 0, 0);
            }
        }
    }

    #pragma unroll
    for (int df = 0; df < 4; df++) {
        int col = h * HD_ + df * 16 + l15;
        #pragma unroll
        for (int j = 0; j < 4; j++) {
            int s = qt * 64 + w * 16 + l4 * 4 + j;
            ctx[((size_t)b * S_ + s) * H_ + col] = f2bf(ctx_acc[df][j] / lrun[j]);
        }
    }
}

// ---------------------------------------------------------------- out proj + residual
__global__ __launch_bounds__(256) void out_proj(
        const ushort* __restrict__ Ctx, const ushort* __restrict__ Wot,
        const float* __restrict__ bo,  const float* __restrict__ Hs,
        float* __restrict__ Tmp) {
    __shared__ ushort As[128][72];
    __shared__ ushort Bs[128][72];
    const int m0 = blockIdx.x * 128, n0 = blockIdx.y * 128;
    const int t = threadIdx.x;
    const int lane = t & 63, w = t >> 6;
    const int wr = (w >> 1) * 64, wc = (w & 1) * 64;
    const int l15 = lane & 15, l4 = lane >> 4;

    f32x4 acc[4][4] = {};
    const int sr = t >> 3, sc = (t & 7) * 8;

    for (int k0 = 0; k0 < H_; k0 += 64) {
        __syncthreads();
        #pragma unroll
        for (int p = 0; p < 4; p++) {
            uint4 av  = *(const uint4*)&Ctx[(m0 + p * 32 + sr) * H_ + k0 + sc];
            uint4 bv2 = *(const uint4*)&Wot[(n0 + p * 32 + sr) * H_ + k0 + sc];
            *(uint4*)&As[p * 32 + sr][sc] = av;
            *(uint4*)&Bs[p * 32 + sr][sc] = bv2;
        }
        __syncthreads();
        #pragma unroll
        for (int ks = 0; ks < 2; ks++) {
            bf16x8 af[4], bfr[4];
            #pragma unroll
            for (int i = 0; i < 4; i++) af[i]  = *(const bf16x8*)&As[wr + i * 16 + l15][ks * 32 + l4 * 8];
            #pragma unroll
            for (int i = 0; i < 4; i++) bfr[i] = *(const bf16x8*)&Bs[wc + i * 16 + l15][ks * 32 + l4 * 8];
            #pragma unroll
            for (int mi = 0; mi < 4; mi++)
                #pragma unroll
                for (int ni = 0; ni < 4; ni++)
                    acc[mi][ni] = __builtin_amdgcn_mfma_f32_16x16x32_bf16(af[mi], bfr[ni], acc[mi][ni], 0, 0, 0);
        }
    }

    #pragma unroll
    for (int ni = 0; ni < 4; ni++) {
        int n = n0 + wc + ni * 16 + l15;
        float bvf = bo[n];
        #pragma unroll
        for (int mi = 0; mi < 4; mi++) {
            int mrow = m0 + wr + mi * 16 + l4 * 4;
            #pragma unroll
            for (int j = 0; j < 4; j++) {
                int m = mrow + j;
                Tmp[(size_t)m * H_ + n] = acc[mi][ni][j] + bvf + Hs[(size_t)m * H_ + n];
            }
        }
    }
}

// ---------------------------------------------------------------- layernorm (fp32 out)
__global__ __launch_bounds__(256) void ln_kernel(
        const float* __restrict__ Tmp, const float* __restrict__ gamma,
        const float* __restrict__ beta, float* __restrict__ Out) {
    const int row = blockIdx.x;
    const float* x = Tmp + (size_t)row * H_;
    const int t = threadIdx.x, w = t >> 6, lane = t & 63;

    float4 v = *(const float4*)&x[t * 4];
    float s = v.x + v.y + v.z + v.w;
    #pragma unroll
    for (int m = 1; m < 64; m <<= 1) s += __shfl_xor(s, m, 64);
    __shared__ float red[4], red2[4];
    if (lane == 0) red[w] = s;
    __syncthreads();
    float mu = (red[0] + red[1] + red[2] + red[3]) * (1.0f / H_);

    float d0 = v.x - mu, d1 = v.y - mu, d2 = v.z - mu, d3 = v.w - mu;
    float sq = d0 * d0 + d1 * d1 + d2 * d2 + d3 * d3;
    #pragma unroll
    for (int m = 1; m < 64; m <<= 1) sq += __shfl_xor(sq, m, 64);
    if (lane == 0) red2[w] = sq;
    __syncthreads();
    float var = (red2[0] + red2[1] + red2[2] + red2[3]) * (1.0f / H_);
    float rstd = rsqrtf(var + EPSLN);

    float dd[4] = {d0, d1, d2, d3};
    float4 o;
    o.x = dd[0] * rstd * gamma[t * 4 + 0] + beta[t * 4 + 0];
    o.y = dd[1] * rstd * gamma[t * 4 + 1] + beta[t * 4 + 1];
    o.z = dd[2] * rstd * gamma[t * 4 + 2] + beta[t * 4 + 2];
    o.w = dd[3] * rstd * gamma[t * 4 + 3] + beta[t * 4 + 3];
    *(float4*)&Out[(size_t)row * H_ + t * 4] = o;
}

// ---------------------------------------------------------------- launch
extern "C" void kernel_launch(void* const* d_in, const int* in_sizes, int n_in,
                              void* d_out, int out_size, void* d_ws, size_t ws_size,
                              hipStream_t stream) {
    const float* hs    = (const float*)d_in[0];
    const float* mask  = (const float*)d_in[1];
    const float* Wq    = (const float*)d_in[2];
    const float* bq    = (const float*)d_in[3];
    const float* Wk    = (const float*)d_in[4];
    const float* bk    = (const float*)d_in[5];
    const float* Wv    = (const float*)d_in[6];
    const float* bv    = (const float*)d_in[7];
    const float* Wo    = (const float*)d_in[8];
    const float* bo    = (const float*)d_in[9];
    const float* gamma = (const float*)d_in[10];
    const float* beta  = (const float*)d_in[11];

    char* ws = (char*)d_ws;
    const size_t WSZ = (size_t)H_ * H_;           // 1M elems
    const size_t TSZ = (size_t)B_ * S_ * H_;      // 4M elems
    ushort* Wqt = (ushort*)ws;
    ushort* Wkt = Wqt + WSZ;
    ushort* Wvt = Wkt + WSZ;
    ushort* Wot = Wvt + WSZ;
    ushort* Xb  = Wot + WSZ;
    ushort* Qb  = Xb + TSZ;
    ushort* Kb  = Qb + TSZ;
    ushort* Vb  = Kb + TSZ;
    ushort* Ctx = Vb + TSZ;
    float*  Tmp = (float*)(Ctx + TSZ);
    // total: 8MB (Wt) + 8MB (Xb) + 32MB (Q,K,V,Ctx) + 16MB (Tmp f32) = 64 MB

    cvt_f32_bf16<<<TSZ / (256 * 4), 256, 0, stream>>>(hs, Xb, (int)TSZ);
    transpose_cvt<<<dim3(16, 16, 4), 256, 0, stream>>>(Wq, Wk, Wv, Wo, Wqt, Wkt, Wvt, Wot);

    qkv_gemm<<<dim3(32, 8, 3), 256, 0, stream>>>(Xb, Wqt, Wkt, Wvt, bq, bk, bv, Qb, Kb, Vb);
    flash_attn<<<dim3(32, 16, 2), 256, 0, stream>>>(Qb, Kb, Vb, mask, Ctx);
    out_proj<<<dim3(32, 8), 256, 0, stream>>>(Ctx, Wot, bo, hs, Tmp);
    ln_kernel<<<B_ * S_, 256, 0, stream>>>(Tmp, gamma, beta, (float*)d_out);
}

// Round 4
// 201.742 us; speedup vs baseline: 1.1721x; 1.1721x over previous
//
#include <hip/hip_runtime.h>
#include <hip/hip_bf16.h>

#define B_  2
#define S_  2048
#define H_  1024
#define NH_ 16
#define HD_ 64
#define EPSLN 1e-12f

typedef short bf16x8 __attribute__((ext_vector_type(8)));
typedef float f32x4  __attribute__((ext_vector_type(4)));

__device__ __forceinline__ float bf2f(ushort u) {
    union { unsigned int i; float f; } v; v.i = ((unsigned int)u) << 16; return v.f;
}
__device__ __forceinline__ ushort f2bf(float f) {
    union { float f; unsigned int i; } v; v.f = f;
    unsigned int r = v.i + 0x7FFFu + ((v.i >> 16) & 1u);   // RNE
    return (ushort)(r >> 16);
}

// ---------------------------------------------------------------- fp32 -> bf16 convert
__global__ __launch_bounds__(256) void cvt_f32_bf16(const float* __restrict__ in,
                                                    ushort* __restrict__ out, int n) {
    int i = (blockIdx.x * 256 + threadIdx.x) * 4;
    float4 v = *(const float4*)&in[i];
    ushort4 o = make_ushort4(f2bf(v.x), f2bf(v.y), f2bf(v.z), f2bf(v.w));
    *(ushort4*)&out[i] = o;
}

// ---------------------------------------------------------------- transpose + convert
// 1024x1024 fp32 -> transposed bf16, 64x64 tiles
__global__ __launch_bounds__(256) void transpose_cvt(
        const float* __restrict__ W0, const float* __restrict__ W1,
        const float* __restrict__ W2, const float* __restrict__ W3,
        ushort* __restrict__ T0, ushort* __restrict__ T1,
        ushort* __restrict__ T2, ushort* __restrict__ T3) {
    const int z = blockIdx.z;
    const float* in = (z == 0) ? W0 : (z == 1) ? W1 : (z == 2) ? W2 : W3;
    ushort* out     = (z == 0) ? T0 : (z == 1) ? T1 : (z == 2) ? T2 : T3;

    __shared__ float tile[64][65];
    const int bx = blockIdx.x * 64, by = blockIdx.y * 64;
    const int t = threadIdx.x;
    #pragma unroll
    for (int i = 0; i < 16; i++) {
        int idx = t + i * 256;           // 0..4095
        int r = idx >> 6, c = idx & 63;
        tile[r][c] = in[(by + r) * 1024 + bx + c];
    }
    __syncthreads();
    #pragma unroll
    for (int i = 0; i < 16; i++) {
        int idx = t + i * 256;
        int r = idx >> 6, c = idx & 63;
        out[(bx + r) * 1024 + by + c] = f2bf(tile[c][r]);
    }
}

// ---------------------------------------------------------------- V transpose (bf16)
// Vb [head][S][64] -> VtG [head][64][S]; per-block: 64 s-rows of one head
__global__ __launch_bounds__(256) void v_transpose(const ushort* __restrict__ Vb,
                                                   ushort* __restrict__ VtG) {
    __shared__ ushort tile[64][72];
    const int s0 = blockIdx.x * 64;
    const int head = blockIdx.y;
    const ushort* src = Vb + (size_t)head * S_ * HD_;
    ushort* dst       = VtG + (size_t)head * S_ * HD_;
    const int t = threadIdx.x, lane = t & 63, w = t >> 6;

    // read: s = s0+lane, d = w*16 + 0..15 (two uint4); scatter-write rows d, col lane
    // (64 lanes span all 64 kv columns -> writes hit all 32 banks, ~2-way = free)
    uint4 a = *(const uint4*)&src[(s0 + lane) * HD_ + w * 16];
    uint4 b = *(const uint4*)&src[(s0 + lane) * HD_ + w * 16 + 8];
    const ushort* pa = (const ushort*)&a;
    #pragma unroll
    for (int i = 0; i < 8; i++) tile[w * 16 + i][lane] = pa[i];
    const ushort* pb = (const ushort*)&b;
    #pragma unroll
    for (int i = 0; i < 8; i++) tile[w * 16 + 8 + i][lane] = pb[i];
    __syncthreads();

    const int d = t >> 2, sc = (t & 3) * 16;
    uint4 o1 = *(const uint4*)&tile[d][sc];
    uint4 o2 = *(const uint4*)&tile[d][sc + 8];
    *(uint4*)&dst[d * S_ + s0 + sc]     = o1;
    *(uint4*)&dst[d * S_ + s0 + sc + 8] = o2;
}

// ---------------------------------------------------------------- QKV GEMM
// X[4096][1024](bf16) @ W (via W^T bf16) + bias(f32) -> [B,NH,S,HD] bf16
__global__ __launch_bounds__(256) void qkv_gemm(
        const ushort* __restrict__ X,
        const ushort* __restrict__ Wqt, const ushort* __restrict__ Wkt, const ushort* __restrict__ Wvt,
        const float* __restrict__ bq,  const float* __restrict__ bk,  const float* __restrict__ bv,
        ushort* __restrict__ Qo, ushort* __restrict__ Ko, ushort* __restrict__ Vo) {
    const int which = blockIdx.z;
    const ushort* Wt  = (which == 0) ? Wqt : (which == 1) ? Wkt : Wvt;
    const float* bias = (which == 0) ? bq  : (which == 1) ? bk  : bv;
    ushort* Out       = (which == 0) ? Qo  : (which == 1) ? Ko  : Vo;

    __shared__ ushort As[128][72];
    __shared__ ushort Bs[128][72];
    const int m0 = blockIdx.x * 128, n0 = blockIdx.y * 128;
    const int t = threadIdx.x;
    const int lane = t & 63, w = t >> 6;
    const int wr = (w >> 1) * 64, wc = (w & 1) * 64;
    const int l15 = lane & 15, l4 = lane >> 4;

    f32x4 acc[4][4] = {};
    const int sr = t >> 3, sc = (t & 7) * 8;

    for (int k0 = 0; k0 < H_; k0 += 64) {
        __syncthreads();
        #pragma unroll
        for (int p = 0; p < 4; p++) {
            uint4 av  = *(const uint4*)&X [(m0 + p * 32 + sr) * H_ + k0 + sc];
            uint4 bv2 = *(const uint4*)&Wt[(n0 + p * 32 + sr) * H_ + k0 + sc];
            *(uint4*)&As[p * 32 + sr][sc] = av;
            *(uint4*)&Bs[p * 32 + sr][sc] = bv2;
        }
        __syncthreads();
        #pragma unroll
        for (int ks = 0; ks < 2; ks++) {
            bf16x8 af[4], bfr[4];
            #pragma unroll
            for (int i = 0; i < 4; i++) af[i]  = *(const bf16x8*)&As[wr + i * 16 + l15][ks * 32 + l4 * 8];
            #pragma unroll
            for (int i = 0; i < 4; i++) bfr[i] = *(const bf16x8*)&Bs[wc + i * 16 + l15][ks * 32 + l4 * 8];
            #pragma unroll
            for (int mi = 0; mi < 4; mi++)
                #pragma unroll
                for (int ni = 0; ni < 4; ni++)
                    acc[mi][ni] = __builtin_amdgcn_mfma_f32_16x16x32_bf16(af[mi], bfr[ni], acc[mi][ni], 0, 0, 0);
        }
    }

    #pragma unroll
    for (int ni = 0; ni < 4; ni++) {
        int n = n0 + wc + ni * 16 + l15;
        float bvf = bias[n];
        int h = n >> 6, d = n & 63;
        #pragma unroll
        for (int mi = 0; mi < 4; mi++) {
            int mrow = m0 + wr + mi * 16 + l4 * 4;
            #pragma unroll
            for (int j = 0; j < 4; j++) {
                int m = mrow + j;
                int b = m >> 11, s = m & 2047;
                Out[((b * NH_ + h) * S_ + s) * HD_ + d] = f2bf(acc[mi][ni][j] + bvf);
            }
        }
    }
}

// ---------------------------------------------------------------- flash attention
// Q,K: [B,NH,S,HD] bf16, VtG: [B,NH,HD,S] bf16, mask f32 -> ctx: [B,S,H] bf16
__global__ __launch_bounds__(256) void flash_attn(
        const ushort* __restrict__ Q, const ushort* __restrict__ K, const ushort* __restrict__ VtG,
        const float* __restrict__ mask, ushort* __restrict__ ctx) {
    __shared__ ushort Ks[64][72];
    __shared__ ushort Vt[64][72];     // [d][kv] (transposed tile)
    __shared__ ushort Ps[4][16][72];

    const int qt = blockIdx.x, h = blockIdx.y, b = blockIdx.z;
    const int t = threadIdx.x, lane = t & 63, w = t >> 6;
    const int l15 = lane & 15, l4 = lane >> 4;
    const size_t head_off = ((size_t)(b * NH_ + h)) * S_ * HD_;
    const ushort* Qh = Q + head_off;
    const ushort* Kh = K + head_off;
    const ushort* Vh = VtG + head_off;   // [64][S]

    const int qrow = qt * 64 + w * 16 + l15;
    bf16x8 qf[2];
    qf[0] = *(const bf16x8*)&Qh[qrow * 64 + 0  + l4 * 8];
    qf[1] = *(const bf16x8*)&Qh[qrow * 64 + 32 + l4 * 8];

    f32x4 ctx_acc[4] = {};
    float mrun[4], lrun[4];
    #pragma unroll
    for (int j = 0; j < 4; j++) { mrun[j] = -1e30f; lrun[j] = 0.f; }

    const int sr = t >> 2, sc0 = (t & 3) * 8;       // K staging
    const int vd = t >> 2, vsc = (t & 3) * 16;      // V^T staging

    for (int kv0 = 0; kv0 < S_; kv0 += 64) {
        __syncthreads();
        {
            uint4 k1 = *(const uint4*)&Kh[(kv0 + sr) * 64 + sc0];
            uint4 k2 = *(const uint4*)&Kh[(kv0 + sr) * 64 + sc0 + 32];
            uint4 v1 = *(const uint4*)&Vh[vd * S_ + kv0 + vsc];
            uint4 v2 = *(const uint4*)&Vh[vd * S_ + kv0 + vsc + 8];
            *(uint4*)&Ks[sr][sc0]      = k1;
            *(uint4*)&Ks[sr][sc0 + 32] = k2;
            *(uint4*)&Vt[vd][vsc]      = v1;
            *(uint4*)&Vt[vd][vsc + 8]  = v2;
        }
        __syncthreads();

        // QK^T: sacc[n] : rows q_local = l4*4+j, cols kv_local = n*16+l15
        f32x4 sacc[4] = {};
        #pragma unroll
        for (int ks = 0; ks < 2; ks++) {
            bf16x8 kf[4];
            #pragma unroll
            for (int n = 0; n < 4; n++) kf[n] = *(const bf16x8*)&Ks[n * 16 + l15][ks * 32 + l4 * 8];
            #pragma unroll
            for (int n = 0; n < 4; n++)
                sacc[n] = __builtin_amdgcn_mfma_f32_16x16x32_bf16(qf[ks], kf[n], sacc[n], 0, 0, 0);
        }

        float sv[4][4], tmax[4];
        #pragma unroll
        for (int j = 0; j < 4; j++) tmax[j] = -1e30f;
        #pragma unroll
        for (int n = 0; n < 4; n++) {
            float mk = mask[b * S_ + kv0 + n * 16 + l15];
            #pragma unroll
            for (int j = 0; j < 4; j++) {
                float x = sacc[n][j] * 0.125f + mk;
                sv[n][j] = x;
                tmax[j] = fmaxf(tmax[j], x);
            }
        }
        #pragma unroll
        for (int m = 1; m < 16; m <<= 1)
            #pragma unroll
            for (int j = 0; j < 4; j++) tmax[j] = fmaxf(tmax[j], __shfl_xor(tmax[j], m, 64));

        float scale_j[4], tsum[4];
        #pragma unroll
        for (int j = 0; j < 4; j++) {
            float mnew = fmaxf(mrun[j], tmax[j]);
            scale_j[j] = __expf(mrun[j] - mnew);
            mrun[j] = mnew;
            tsum[j] = 0.f;
        }
        #pragma unroll
        for (int n = 0; n < 4; n++)
            #pragma unroll
            for (int j = 0; j < 4; j++) {
                float p = __expf(sv[n][j] - mrun[j]);
                tsum[j] += p;
                Ps[w][l4 * 4 + j][n * 16 + l15] = f2bf(p);
            }
        #pragma unroll
        for (int m = 1; m < 16; m <<= 1)
            #pragma unroll
            for (int j = 0; j < 4; j++) tsum[j] += __shfl_xor(tsum[j], m, 64);
        #pragma unroll
        for (int j = 0; j < 4; j++) lrun[j] = lrun[j] * scale_j[j] + tsum[j];

        #pragma unroll
        for (int df = 0; df < 4; df++)
            #pragma unroll
            for (int j = 0; j < 4; j++) ctx_acc[df][j] *= scale_j[j];

        // PV: B-fragment = contiguous bf16x8 from V^T tile
        #pragma unroll
        for (int ks = 0; ks < 2; ks++) {
            bf16x8 pf = *(const bf16x8*)&Ps[w][l15][ks * 32 + l4 * 8];
            #pragma unroll
            for (int df = 0; df < 4; df++) {
                bf16x8 vf = *(const bf16x8*)&Vt[df * 16 + l15][ks * 32 + l4 * 8];
                ctx_acc[df] = __builtin_amdgcn_mfma_f32_16x16x32_bf16(pf, vf, ctx_acc[df], 0, 0, 0);
            }
        }
    }

    #pragma unroll
    for (int df = 0; df < 4; df++) {
        int col = h * HD_ + df * 16 + l15;
        #pragma unroll
        for (int j = 0; j < 4; j++) {
            int s = qt * 64 + w * 16 + l4 * 4 + j;
            ctx[((size_t)b * S_ + s) * H_ + col] = f2bf(ctx_acc[df][j] / lrun[j]);
        }
    }
}

// ---------------------------------------------------------------- out proj + residual
__global__ __launch_bounds__(256) void out_proj(
        const ushort* __restrict__ Ctx, const ushort* __restrict__ Wot,
        const float* __restrict__ bo,  const float* __restrict__ Hs,
        float* __restrict__ Tmp) {
    __shared__ ushort As[128][72];
    __shared__ ushort Bs[128][72];
    const int m0 = blockIdx.x * 128, n0 = blockIdx.y * 128;
    const int t = threadIdx.x;
    const int lane = t & 63, w = t >> 6;
    const int wr = (w >> 1) * 64, wc = (w & 1) * 64;
    const int l15 = lane & 15, l4 = lane >> 4;

    f32x4 acc[4][4] = {};
    const int sr = t >> 3, sc = (t & 7) * 8;

    for (int k0 = 0; k0 < H_; k0 += 64) {
        __syncthreads();
        #pragma unroll
        for (int p = 0; p < 4; p++) {
            uint4 av  = *(const uint4*)&Ctx[(m0 + p * 32 + sr) * H_ + k0 + sc];
            uint4 bv2 = *(const uint4*)&Wot[(n0 + p * 32 + sr) * H_ + k0 + sc];
            *(uint4*)&As[p * 32 + sr][sc] = av;
            *(uint4*)&Bs[p * 32 + sr][sc] = bv2;
        }
        __syncthreads();
        #pragma unroll
        for (int ks = 0; ks < 2; ks++) {
            bf16x8 af[4], bfr[4];
            #pragma unroll
            for (int i = 0; i < 4; i++) af[i]  = *(const bf16x8*)&As[wr + i * 16 + l15][ks * 32 + l4 * 8];
            #pragma unroll
            for (int i = 0; i < 4; i++) bfr[i] = *(const bf16x8*)&Bs[wc + i * 16 + l15][ks * 32 + l4 * 8];
            #pragma unroll
            for (int mi = 0; mi < 4; mi++)
                #pragma unroll
                for (int ni = 0; ni < 4; ni++)
                    acc[mi][ni] = __builtin_amdgcn_mfma_f32_16x16x32_bf16(af[mi], bfr[ni], acc[mi][ni], 0, 0, 0);
        }
    }

    #pragma unroll
    for (int ni = 0; ni < 4; ni++) {
        int n = n0 + wc + ni * 16 + l15;
        float bvf = bo[n];
        #pragma unroll
        for (int mi = 0; mi < 4; mi++) {
            int mrow = m0 + wr + mi * 16 + l4 * 4;
            #pragma unroll
            for (int j = 0; j < 4; j++) {
                int m = mrow + j;
                Tmp[(size_t)m * H_ + n] = acc[mi][ni][j] + bvf + Hs[(size_t)m * H_ + n];
            }
        }
    }
}

// ---------------------------------------------------------------- layernorm (fp32 out)
__global__ __launch_bounds__(256) void ln_kernel(
        const float* __restrict__ Tmp, const float* __restrict__ gamma,
        const float* __restrict__ beta, float* __restrict__ Out) {
    const int row = blockIdx.x;
    const float* x = Tmp + (size_t)row * H_;
    const int t = threadIdx.x, w = t >> 6, lane = t & 63;

    float4 v = *(const float4*)&x[t * 4];
    float s = v.x + v.y + v.z + v.w;
    #pragma unroll
    for (int m = 1; m < 64; m <<= 1) s += __shfl_xor(s, m, 64);
    __shared__ float red[4], red2[4];
    if (lane == 0) red[w] = s;
    __syncthreads();
    float mu = (red[0] + red[1] + red[2] + red[3]) * (1.0f / H_);

    float d0 = v.x - mu, d1 = v.y - mu, d2 = v.z - mu, d3 = v.w - mu;
    float sq = d0 * d0 + d1 * d1 + d2 * d2 + d3 * d3;
    #pragma unroll
    for (int m = 1; m < 64; m <<= 1) sq += __shfl_xor(sq, m, 64);
    if (lane == 0) red2[w] = sq;
    __syncthreads();
    float var = (red2[0] + red2[1] + red2[2] + red2[3]) * (1.0f / H_);
    float rstd = rsqrtf(var + EPSLN);

    float dd[4] = {d0, d1, d2, d3};
    float4 o;
    o.x = dd[0] * rstd * gamma[t * 4 + 0] + beta[t * 4 + 0];
    o.y = dd[1] * rstd * gamma[t * 4 + 1] + beta[t * 4 + 1];
    o.z = dd[2] * rstd * gamma[t * 4 + 2] + beta[t * 4 + 2];
    o.w = dd[3] * rstd * gamma[t * 4 + 3] + beta[t * 4 + 3];
    *(float4*)&Out[(size_t)row * H_ + t * 4] = o;
}

// ---------------------------------------------------------------- launch
extern "C" void kernel_launch(void* const* d_in, const int* in_sizes, int n_in,
                              void* d_out, int out_size, void* d_ws, size_t ws_size,
                              hipStream_t stream) {
    const float* hs    = (const float*)d_in[0];
    const float* mask  = (const float*)d_in[1];
    const float* Wq    = (const float*)d_in[2];
    const float* bq    = (const float*)d_in[3];
    const float* Wk    = (const float*)d_in[4];
    const float* bk    = (const float*)d_in[5];
    const float* Wv    = (const float*)d_in[6];
    const float* bv    = (const float*)d_in[7];
    const float* Wo    = (const float*)d_in[8];
    const float* bo    = (const float*)d_in[9];
    const float* gamma = (const float*)d_in[10];
    const float* beta  = (const float*)d_in[11];

    char* ws = (char*)d_ws;
    const size_t WSZ = (size_t)H_ * H_;           // 1M elems
    const size_t TSZ = (size_t)B_ * S_ * H_;      // 4M elems
    ushort* Wqt = (ushort*)ws;
    ushort* Wkt = Wqt + WSZ;
    ushort* Wvt = Wkt + WSZ;
    ushort* Wot = Wvt + WSZ;
    ushort* Xb  = Wot + WSZ;
    ushort* Qb  = Xb + TSZ;
    ushort* Kb  = Qb + TSZ;
    ushort* Vb  = Kb + TSZ;
    ushort* Ctx = Vb + TSZ;
    float*  Tmp = (float*)(Ctx + TSZ);
    ushort* VtG = (ushort*)Tmp;   // alias: VtG (8MB) lives in Tmp's 16MB region;
                                  // VtG is dead before out_proj writes Tmp.
    // total: 8MB (Wt) + 8MB (Xb) + 32MB (Q,K,V,Ctx) + 16MB (Tmp f32) = 64 MB

    cvt_f32_bf16<<<TSZ / (256 * 4), 256, 0, stream>>>(hs, Xb, (int)TSZ);
    transpose_cvt<<<dim3(16, 16, 4), 256, 0, stream>>>(Wq, Wk, Wv, Wo, Wqt, Wkt, Wvt, Wot);

    qkv_gemm<<<dim3(32, 8, 3), 256, 0, stream>>>(Xb, Wqt, Wkt, Wvt, bq, bk, bv, Qb, Kb, Vb);
    v_transpose<<<dim3(S_ / 64, B_ * NH_), 256, 0, stream>>>(Vb, VtG);
    flash_attn<<<dim3(32, 16, 2), 256, 0, stream>>>(Qb, Kb, VtG, mask, Ctx);
    out_proj<<<dim3(32, 8), 256, 0, stream>>>(Ctx, Wot, bo, hs, Tmp);
    ln_kernel<<<B_ * S_, 256, 0, stream>>>(Tmp, gamma, beta, (float*)d_out);
}

// Round 5
// 168.434 us; speedup vs baseline: 1.4039x; 1.1978x over previous
//
#include <hip/hip_runtime.h>
#include <hip/hip_bf16.h>

#define B_  2
#define S_  2048
#define H_  1024
#define NH_ 16
#define HD_ 64
#define EPSLN 1e-12f

typedef short bf16x8 __attribute__((ext_vector_type(8)));
typedef float f32x4  __attribute__((ext_vector_type(4)));

__device__ __forceinline__ float bf2f(ushort u) {
    union { unsigned int i; float f; } v; v.i = ((unsigned int)u) << 16; return v.f;
}
__device__ __forceinline__ ushort f2bf(float f) {
    union { float f; unsigned int i; } v; v.f = f;
    unsigned int r = v.i + 0x7FFFu + ((v.i >> 16) & 1u);   // RNE
    return (ushort)(r >> 16);
}
// HW convert (v_cvt_pk_bf16_f32-friendly)
__device__ __forceinline__ ushort f2bf_hw(float f) {
    __hip_bfloat16 h = __float2bfloat16(f);
    return *reinterpret_cast<ushort*>(&h);
}
__device__ __forceinline__ unsigned int pack_bf2(float a, float b) {
    return ((unsigned int)f2bf_hw(b) << 16) | (unsigned int)f2bf_hw(a);
}

// ---------------------------------------------------------------- fp32 -> bf16 convert
__global__ __launch_bounds__(256) void cvt_f32_bf16(const float* __restrict__ in,
                                                    ushort* __restrict__ out, int n) {
    int i = (blockIdx.x * 256 + threadIdx.x) * 4;
    float4 v = *(const float4*)&in[i];
    ushort4 o = make_ushort4(f2bf(v.x), f2bf(v.y), f2bf(v.z), f2bf(v.w));
    *(ushort4*)&out[i] = o;
}

// ---------------------------------------------------------------- transpose + convert
// 1024x1024 fp32 -> transposed bf16, 64x64 tiles
__global__ __launch_bounds__(256) void transpose_cvt(
        const float* __restrict__ W0, const float* __restrict__ W1,
        const float* __restrict__ W2, const float* __restrict__ W3,
        ushort* __restrict__ T0, ushort* __restrict__ T1,
        ushort* __restrict__ T2, ushort* __restrict__ T3) {
    const int z = blockIdx.z;
    const float* in = (z == 0) ? W0 : (z == 1) ? W1 : (z == 2) ? W2 : W3;
    ushort* out     = (z == 0) ? T0 : (z == 1) ? T1 : (z == 2) ? T2 : T3;

    __shared__ float tile[64][65];
    const int bx = blockIdx.x * 64, by = blockIdx.y * 64;
    const int t = threadIdx.x;
    #pragma unroll
    for (int i = 0; i < 16; i++) {
        int idx = t + i * 256;           // 0..4095
        int r = idx >> 6, c = idx & 63;
        tile[r][c] = in[(by + r) * 1024 + bx + c];
    }
    __syncthreads();
    #pragma unroll
    for (int i = 0; i < 16; i++) {
        int idx = t + i * 256;
        int r = idx >> 6, c = idx & 63;
        out[(bx + r) * 1024 + by + c] = f2bf(tile[c][r]);
    }
}

// ---------------------------------------------------------------- V transpose (bf16)
// Vb [head][S][64] -> VtG [head][64][S]; per-block: 64 s-rows of one head
__global__ __launch_bounds__(256) void v_transpose(const ushort* __restrict__ Vb,
                                                   ushort* __restrict__ VtG) {
    __shared__ ushort tile[64][72];
    const int s0 = blockIdx.x * 64;
    const int head = blockIdx.y;
    const ushort* src = Vb + (size_t)head * S_ * HD_;
    ushort* dst       = VtG + (size_t)head * S_ * HD_;
    const int t = threadIdx.x, lane = t & 63, w = t >> 6;

    uint4 a = *(const uint4*)&src[(s0 + lane) * HD_ + w * 16];
    uint4 b = *(const uint4*)&src[(s0 + lane) * HD_ + w * 16 + 8];
    const ushort* pa = (const ushort*)&a;
    #pragma unroll
    for (int i = 0; i < 8; i++) tile[w * 16 + i][lane] = pa[i];
    const ushort* pb = (const ushort*)&b;
    #pragma unroll
    for (int i = 0; i < 8; i++) tile[w * 16 + 8 + i][lane] = pb[i];
    __syncthreads();

    const int d = t >> 2, sc = (t & 3) * 16;
    uint4 o1 = *(const uint4*)&tile[d][sc];
    uint4 o2 = *(const uint4*)&tile[d][sc + 8];
    *(uint4*)&dst[d * S_ + s0 + sc]     = o1;
    *(uint4*)&dst[d * S_ + s0 + sc + 8] = o2;
}

// ---------------------------------------------------------------- QKV GEMM
// X[4096][1024](bf16) @ W (via W^T bf16) + bias(f32) -> [B,NH,S,HD] bf16
__global__ __launch_bounds__(256) void qkv_gemm(
        const ushort* __restrict__ X,
        const ushort* __restrict__ Wqt, const ushort* __restrict__ Wkt, const ushort* __restrict__ Wvt,
        const float* __restrict__ bq,  const float* __restrict__ bk,  const float* __restrict__ bv,
        ushort* __restrict__ Qo, ushort* __restrict__ Ko, ushort* __restrict__ Vo) {
    const int which = blockIdx.z;
    const ushort* Wt  = (which == 0) ? Wqt : (which == 1) ? Wkt : Wvt;
    const float* bias = (which == 0) ? bq  : (which == 1) ? bk  : bv;
    ushort* Out       = (which == 0) ? Qo  : (which == 1) ? Ko  : Vo;

    __shared__ ushort As[128][72];
    __shared__ ushort Bs[128][72];
    const int m0 = blockIdx.x * 128, n0 = blockIdx.y * 128;
    const int t = threadIdx.x;
    const int lane = t & 63, w = t >> 6;
    const int wr = (w >> 1) * 64, wc = (w & 1) * 64;
    const int l15 = lane & 15, l4 = lane >> 4;

    f32x4 acc[4][4] = {};
    const int sr = t >> 3, sc = (t & 7) * 8;

    for (int k0 = 0; k0 < H_; k0 += 64) {
        __syncthreads();
        #pragma unroll
        for (int p = 0; p < 4; p++) {
            uint4 av  = *(const uint4*)&X [(m0 + p * 32 + sr) * H_ + k0 + sc];
            uint4 bv2 = *(const uint4*)&Wt[(n0 + p * 32 + sr) * H_ + k0 + sc];
            *(uint4*)&As[p * 32 + sr][sc] = av;
            *(uint4*)&Bs[p * 32 + sr][sc] = bv2;
        }
        __syncthreads();
        #pragma unroll
        for (int ks = 0; ks < 2; ks++) {
            bf16x8 af[4], bfr[4];
            #pragma unroll
            for (int i = 0; i < 4; i++) af[i]  = *(const bf16x8*)&As[wr + i * 16 + l15][ks * 32 + l4 * 8];
            #pragma unroll
            for (int i = 0; i < 4; i++) bfr[i] = *(const bf16x8*)&Bs[wc + i * 16 + l15][ks * 32 + l4 * 8];
            #pragma unroll
            for (int mi = 0; mi < 4; mi++)
                #pragma unroll
                for (int ni = 0; ni < 4; ni++)
                    acc[mi][ni] = __builtin_amdgcn_mfma_f32_16x16x32_bf16(af[mi], bfr[ni], acc[mi][ni], 0, 0, 0);
        }
    }

    #pragma unroll
    for (int ni = 0; ni < 4; ni++) {
        int n = n0 + wc + ni * 16 + l15;
        float bvf = bias[n];
        int h = n >> 6, d = n & 63;
        #pragma unroll
        for (int mi = 0; mi < 4; mi++) {
            int mrow = m0 + wr + mi * 16 + l4 * 4;
            #pragma unroll
            for (int j = 0; j < 4; j++) {
                int m = mrow + j;
                int b = m >> 11, s = m & 2047;
                Out[((b * NH_ + h) * S_ + s) * HD_ + d] = f2bf(acc[mi][ni][j] + bvf);
            }
        }
    }
}

// ---------------------------------------------------------------- flash attention
// Q,K: [B,NH,S,HD] bf16, VtG: [B,NH,HD,S] bf16, mask f32 -> ctx: [B,S,H] bf16
// Swapped QK^T (P^T in registers): thread (l15,l4) holds P[kv=n*16+l4*4+j][q=l15]
__global__ __launch_bounds__(256) void flash_attn(
        const ushort* __restrict__ Q, const ushort* __restrict__ K, const ushort* __restrict__ VtG,
        const float* __restrict__ mask, ushort* __restrict__ ctx) {
    __shared__ __align__(16) ushort Ks[64][72];
    __shared__ __align__(16) ushort Vt[64][72];     // [d][kv] (transposed tile)
    __shared__ __align__(16) ushort Ps[4][16][72];  // per-wave: [q][kv]

    const int qt = blockIdx.x, h = blockIdx.y, b = blockIdx.z;
    const int t = threadIdx.x, lane = t & 63, w = t >> 6;
    const int l15 = lane & 15, l4 = lane >> 4;
    const size_t head_off = ((size_t)(b * NH_ + h)) * S_ * HD_;
    const ushort* Qh = Q + head_off;
    const ushort* Kh = K + head_off;
    const ushort* Vh = VtG + head_off;   // [64][S]

    const int qrow = qt * 64 + w * 16 + l15;
    bf16x8 qf[2];
    qf[0] = *(const bf16x8*)&Qh[qrow * 64 + 0  + l4 * 8];
    qf[1] = *(const bf16x8*)&Qh[qrow * 64 + 32 + l4 * 8];

    f32x4 ctx_acc[4] = {};
    float mrun = -1e30f, lrun = 0.f;   // for q = l15 (this thread's row)

    const int sr = t >> 2, sc0 = (t & 3) * 8;       // K staging
    const int vd = t >> 2, vsc = (t & 3) * 16;      // V^T staging

    for (int kv0 = 0; kv0 < S_; kv0 += 64) {
        __syncthreads();
        {
            uint4 k1 = *(const uint4*)&Kh[(kv0 + sr) * 64 + sc0];
            uint4 k2 = *(const uint4*)&Kh[(kv0 + sr) * 64 + sc0 + 32];
            uint4 v1 = *(const uint4*)&Vh[vd * S_ + kv0 + vsc];
            uint4 v2 = *(const uint4*)&Vh[vd * S_ + kv0 + vsc + 8];
            *(uint4*)&Ks[sr][sc0]      = k1;
            *(uint4*)&Ks[sr][sc0 + 32] = k2;
            *(uint4*)&Vt[vd][vsc]      = v1;
            *(uint4*)&Vt[vd][vsc + 8]  = v2;
        }
        __syncthreads();

        // swapped QK^T: sacc[n][j] = S[kv = n*16 + l4*4 + j][q = l15]
        f32x4 sacc[4] = {};
        #pragma unroll
        for (int ks = 0; ks < 2; ks++) {
            bf16x8 kf[4];
            #pragma unroll
            for (int n = 0; n < 4; n++) kf[n] = *(const bf16x8*)&Ks[n * 16 + l15][ks * 32 + l4 * 8];
            #pragma unroll
            for (int n = 0; n < 4; n++)
                sacc[n] = __builtin_amdgcn_mfma_f32_16x16x32_bf16(kf[n], qf[ks], sacc[n], 0, 0, 0);
        }

        // scale + mask; per-thread max over its 16 kv values
        float tmax = -1e30f;
        #pragma unroll
        for (int n = 0; n < 4; n++) {
            float4 mk4 = *(const float4*)&mask[b * S_ + kv0 + n * 16 + l4 * 4];
            sacc[n][0] = sacc[n][0] * 0.125f + mk4.x;
            sacc[n][1] = sacc[n][1] * 0.125f + mk4.y;
            sacc[n][2] = sacc[n][2] * 0.125f + mk4.z;
            sacc[n][3] = sacc[n][3] * 0.125f + mk4.w;
            tmax = fmaxf(tmax, fmaxf(fmaxf(sacc[n][0], sacc[n][1]), fmaxf(sacc[n][2], sacc[n][3])));
        }
        // reduce across the 4 l4-groups (lanes l15, l15+16, l15+32, l15+48)
        tmax = fmaxf(tmax, __shfl_xor(tmax, 16, 64));
        tmax = fmaxf(tmax, __shfl_xor(tmax, 32, 64));

        float mnew = fmaxf(mrun, tmax);
        float scale = __expf(mrun - mnew);
        mrun = mnew;

        float tsum = 0.f;
        #pragma unroll
        for (int n = 0; n < 4; n++) {
            float p0 = __expf(sacc[n][0] - mnew);
            float p1 = __expf(sacc[n][1] - mnew);
            float p2 = __expf(sacc[n][2] - mnew);
            float p3 = __expf(sacc[n][3] - mnew);
            tsum += (p0 + p1) + (p2 + p3);
            // P^T -> Ps[q=l15][kv]: j=0..3 contiguous -> one b64 write
            uint2 pw = make_uint2(pack_bf2(p0, p1), pack_bf2(p2, p3));
            *(uint2*)&Ps[w][l15][n * 16 + l4 * 4] = pw;
        }
        tsum += __shfl_xor(tsum, 16, 64);
        tsum += __shfl_xor(tsum, 32, 64);
        lrun = lrun * scale + tsum;

        // rescale ctx: ctx_acc rows are q = l4*4+j -> fetch that row's scale
        float sj[4];
        #pragma unroll
        for (int j = 0; j < 4; j++) sj[j] = __shfl(scale, l4 * 4 + j, 64);
        #pragma unroll
        for (int df = 0; df < 4; df++)
            #pragma unroll
            for (int j = 0; j < 4; j++) ctx_acc[df][j] *= sj[j];

        // PV: A = P rows q (b128 reads), B = V^T tile
        #pragma unroll
        for (int ks = 0; ks < 2; ks++) {
            bf16x8 pf = *(const bf16x8*)&Ps[w][l15][ks * 32 + l4 * 8];
            #pragma unroll
            for (int df = 0; df < 4; df++) {
                bf16x8 vf = *(const bf16x8*)&Vt[df * 16 + l15][ks * 32 + l4 * 8];
                ctx_acc[df] = __builtin_amdgcn_mfma_f32_16x16x32_bf16(pf, vf, ctx_acc[df], 0, 0, 0);
            }
        }
    }

    // epilogue: ctx_acc[df][j] is q = l4*4+j, d = df*16+l15
    float lr[4];
    #pragma unroll
    for (int j = 0; j < 4; j++) lr[j] = 1.0f / __shfl(lrun, l4 * 4 + j, 64);
    #pragma unroll
    for (int df = 0; df < 4; df++) {
        int col = h * HD_ + df * 16 + l15;
        #pragma unroll
        for (int j = 0; j < 4; j++) {
            int s = qt * 64 + w * 16 + l4 * 4 + j;
            ctx[((size_t)b * S_ + s) * H_ + col] = f2bf(ctx_acc[df][j] * lr[j]);
        }
    }
}

// ---------------------------------------------------------------- out proj + residual
__global__ __launch_bounds__(256) void out_proj(
        const ushort* __restrict__ Ctx, const ushort* __restrict__ Wot,
        const float* __restrict__ bo,  const float* __restrict__ Hs,
        float* __restrict__ Tmp) {
    __shared__ ushort As[128][72];
    __shared__ ushort Bs[128][72];
    const int m0 = blockIdx.x * 128, n0 = blockIdx.y * 128;
    const int t = threadIdx.x;
    const int lane = t & 63, w = t >> 6;
    const int wr = (w >> 1) * 64, wc = (w & 1) * 64;
    const int l15 = lane & 15, l4 = lane >> 4;

    f32x4 acc[4][4] = {};
    const int sr = t >> 3, sc = (t & 7) * 8;

    for (int k0 = 0; k0 < H_; k0 += 64) {
        __syncthreads();
        #pragma unroll
        for (int p = 0; p < 4; p++) {
            uint4 av  = *(const uint4*)&Ctx[(m0 + p * 32 + sr) * H_ + k0 + sc];
            uint4 bv2 = *(const uint4*)&Wot[(n0 + p * 32 + sr) * H_ + k0 + sc];
            *(uint4*)&As[p * 32 + sr][sc] = av;
            *(uint4*)&Bs[p * 32 + sr][sc] = bv2;
        }
        __syncthreads();
        #pragma unroll
        for (int ks = 0; ks < 2; ks++) {
            bf16x8 af[4], bfr[4];
            #pragma unroll
            for (int i = 0; i < 4; i++) af[i]  = *(const bf16x8*)&As[wr + i * 16 + l15][ks * 32 + l4 * 8];
            #pragma unroll
            for (int i = 0; i < 4; i++) bfr[i] = *(const bf16x8*)&Bs[wc + i * 16 + l15][ks * 32 + l4 * 8];
            #pragma unroll
            for (int mi = 0; mi < 4; mi++)
                #pragma unroll
                for (int ni = 0; ni < 4; ni++)
                    acc[mi][ni] = __builtin_amdgcn_mfma_f32_16x16x32_bf16(af[mi], bfr[ni], acc[mi][ni], 0, 0, 0);
        }
    }

    #pragma unroll
    for (int ni = 0; ni < 4; ni++) {
        int n = n0 + wc + ni * 16 + l15;
        float bvf = bo[n];
        #pragma unroll
        for (int mi = 0; mi < 4; mi++) {
            int mrow = m0 + wr + mi * 16 + l4 * 4;
            #pragma unroll
            for (int j = 0; j < 4; j++) {
                int m = mrow + j;
                Tmp[(size_t)m * H_ + n] = acc[mi][ni][j] + bvf + Hs[(size_t)m * H_ + n];
            }
        }
    }
}

// ---------------------------------------------------------------- layernorm (fp32 out)
__global__ __launch_bounds__(256) void ln_kernel(
        const float* __restrict__ Tmp, const float* __restrict__ gamma,
        const float* __restrict__ beta, float* __restrict__ Out) {
    const int row = blockIdx.x;
    const float* x = Tmp + (size_t)row * H_;
    const int t = threadIdx.x, w = t >> 6, lane = t & 63;

    float4 v = *(const float4*)&x[t * 4];
    float s = v.x + v.y + v.z + v.w;
    #pragma unroll
    for (int m = 1; m < 64; m <<= 1) s += __shfl_xor(s, m, 64);
    __shared__ float red[4], red2[4];
    if (lane == 0) red[w] = s;
    __syncthreads();
    float mu = (red[0] + red[1] + red[2] + red[3]) * (1.0f / H_);

    float d0 = v.x - mu, d1 = v.y - mu, d2 = v.z - mu, d3 = v.w - mu;
    float sq = d0 * d0 + d1 * d1 + d2 * d2 + d3 * d3;
    #pragma unroll
    for (int m = 1; m < 64; m <<= 1) sq += __shfl_xor(sq, m, 64);
    if (lane == 0) red2[w] = sq;
    __syncthreads();
    float var = (red2[0] + red2[1] + red2[2] + red2[3]) * (1.0f / H_);
    float rstd = rsqrtf(var + EPSLN);

    float dd[4] = {d0, d1, d2, d3};
    float4 o;
    o.x = dd[0] * rstd * gamma[t * 4 + 0] + beta[t * 4 + 0];
    o.y = dd[1] * rstd * gamma[t * 4 + 1] + beta[t * 4 + 1];
    o.z = dd[2] * rstd * gamma[t * 4 + 2] + beta[t * 4 + 2];
    o.w = dd[3] * rstd * gamma[t * 4 + 3] + beta[t * 4 + 3];
    *(float4*)&Out[(size_t)row * H_ + t * 4] = o;
}

// ---------------------------------------------------------------- launch
extern "C" void kernel_launch(void* const* d_in, const int* in_sizes, int n_in,
                              void* d_out, int out_size, void* d_ws, size_t ws_size,
                              hipStream_t stream) {
    const float* hs    = (const float*)d_in[0];
    const float* mask  = (const float*)d_in[1];
    const float* Wq    = (const float*)d_in[2];
    const float* bq    = (const float*)d_in[3];
    const float* Wk    = (const float*)d_in[4];
    const float* bk    = (const float*)d_in[5];
    const float* Wv    = (const float*)d_in[6];
    const float* bv    = (const float*)d_in[7];
    const float* Wo    = (const float*)d_in[8];
    const float* bo    = (const float*)d_in[9];
    const float* gamma = (const float*)d_in[10];
    const float* beta  = (const float*)d_in[11];

    char* ws = (char*)d_ws;
    const size_t WSZ = (size_t)H_ * H_;           // 1M elems
    const size_t TSZ = (size_t)B_ * S_ * H_;      // 4M elems
    ushort* Wqt = (ushort*)ws;
    ushort* Wkt = Wqt + WSZ;
    ushort* Wvt = Wkt + WSZ;
    ushort* Wot = Wvt + WSZ;
    ushort* Xb  = Wot + WSZ;
    ushort* Qb  = Xb + TSZ;
    ushort* Kb  = Qb + TSZ;
    ushort* Vb  = Kb + TSZ;
    ushort* Ctx = Vb + TSZ;
    float*  Tmp = (float*)(Ctx + TSZ);
    ushort* VtG = (ushort*)Tmp;   // alias: VtG (8MB) lives in Tmp's 16MB region;
                                  // VtG is dead before out_proj writes Tmp.

    cvt_f32_bf16<<<TSZ / (256 * 4), 256, 0, stream>>>(hs, Xb, (int)TSZ);
    transpose_cvt<<<dim3(16, 16, 4), 256, 0, stream>>>(Wq, Wk, Wv, Wo, Wqt, Wkt, Wvt, Wot);

    qkv_gemm<<<dim3(32, 8, 3), 256, 0, stream>>>(Xb, Wqt, Wkt, Wvt, bq, bk, bv, Qb, Kb, Vb);
    v_transpose<<<dim3(S_ / 64, B_ * NH_), 256, 0, stream>>>(Vb, VtG);
    flash_attn<<<dim3(32, 16, 2), 256, 0, stream>>>(Qb, Kb, VtG, mask, Ctx);
    out_proj<<<dim3(32, 8), 256, 0, stream>>>(Ctx, Wot, bo, hs, Tmp);
    ln_kernel<<<B_ * S_, 256, 0, stream>>>(Tmp, gamma, beta, (float*)d_out);
}